// Round 14
// baseline (3296.438 us; speedup 1.0000x reference)
//
#include <hip/hip_runtime.h>
#include <stdint.h>

// PointerNet fused forward. B=512, S=50, E=H=128.
// R14 = R7 (proven best: 256 blocks x 512 threads, 2 be/block, amortized
// quarter-split f64 dots) + RANK-2 INPUT COLLAPSE:
//   embedded[b,t] = x0*emb0 + x1*emb1  =>  Wih@embedded = x0*(Wih@emb0) +
//   x1*(Wih@emb1). prep precomputes PXE/PXD[2][512] (f64) and
//   PXDS[512] = dWih@dec_start, so the whole x-side LSTM matvec becomes
//   2 scalar f64 FMAs per gate row. Halves LSTM FMA work + LSTM weight L2
//   traffic; removes sh_x and 2 barriers/step (enc 3->2, dec 10->9).
// Numerics: only deviation vs R7 is skipping the f32-rounding of embedded
// before the dot (~1e-8 logit shift; idx margin is O(1) gumbel gaps).
// Everything else verbatim R7: h-side quarter dots + xor16/xor32 butterfly,
// gate sum f_add(f_add(f_add((float)dx,bih),(float)eh),bhh), XLA tanh poly,
// logistic-as-tanh, sequential softmax sums, f64 attention dots.
// Sampling: jax.random.categorical, THREEFRY PARTITIONABLE mode:
//   fold_in: key' = tf2x32(key, (0, t))
//   split (foldlike): k1 = tf2x32(key', (0, 0))   [both output words]
//   random_bits(32): bits[j] = o0 ^ o1 of tf2x32(k1, (0, j))
// gumbel exactly as jax._src.random; argmax with first-index ties.
// All cross-lane communication: LDS write -> __syncthreads -> read, or
// register shuffles (round-5 hardening).

#define OFF_PIH_E 0
#define OFF_PHH_E 65536
#define OFF_PIH_D 131072
#define OFF_PHH_D 196608
#define OFF_PQG   262144
#define OFF_PRG   278528
#define OFF_PQP   294912
#define OFF_PRP   311296
#define OFF_PX    327680   // doubles from here: PXE[1024], PXD[1024], PXDS[512]
// ws total: 327680 floats + 2560 doubles = 1.33 MB

#define RSTR 132   // LDS row stride for RG/RP (16B-aligned)

#define TINYF 1.1754943508222875e-38f

static __device__ __forceinline__ float f_add(float a, float b){ return __fadd_rn(a,b); }
static __device__ __forceinline__ float f_mul(float a, float b){ return __fmul_rn(a,b); }
static __device__ __forceinline__ float f_sub(float a, float b){ return __fsub_rn(a,b); }

static __device__ __forceinline__ double shfl_xor_d(double v, int mask) {
  long long x = __double_as_longlong(v);
  int lo = (int)(x & 0xffffffffll);
  int hi = (int)(x >> 32);
  lo = __shfl_xor(lo, mask);
  hi = __shfl_xor(hi, mask);
  return __longlong_as_double(((long long)hi << 32) | (unsigned long long)(unsigned int)lo);
}
#define RED2(x) { x += shfl_xor_d(x, 16); x += shfl_xor_d(x, 32); }

// XLA CPU tanh: elemental_ir_emitter rational approximation, unfused mul/add.
static __device__ __forceinline__ float tanh_xla(float x) {
  float xc = fminf(fmaxf(x, -7.90531110763549805f), 7.90531110763549805f);
  float x2 = f_mul(xc, xc);
  float p;
  p = -2.76076847742355e-16f;
  p = f_add(f_mul(p, x2),  2.00018790482477e-13f);
  p = f_add(f_mul(p, x2), -8.60467152213735e-11f);
  p = f_add(f_mul(p, x2),  5.12229709037114e-08f);
  p = f_add(f_mul(p, x2),  1.48572235717979e-05f);
  p = f_add(f_mul(p, x2),  6.37261928875436e-04f);
  p = f_add(f_mul(p, x2),  4.89352455891786e-03f);
  p = f_mul(xc, p);
  float q;
  q = 1.19825839466702e-06f;
  q = f_add(f_mul(q, x2), 1.18534705686654e-04f);
  q = f_add(f_mul(q, x2), 2.26843463243900e-03f);
  q = f_add(f_mul(q, x2), 4.89352518554385e-03f);
  float r = __fdiv_rn(p, q);
  return (fabsf(x) < 0.0004f) ? x : r;
}

// XLA logistic expansion: 0.5 + 0.5*tanh(0.5*x)
static __device__ __forceinline__ float sigmoid_xla(float x) {
  return f_add(0.5f, f_mul(0.5f, tanh_xla(f_mul(0.5f, x))));
}

// Threefry-2x32, 20 rounds (JAX key schedule)
static __device__ __forceinline__ void tf2x32(uint32_t k0, uint32_t k1,
                                              uint32_t x0, uint32_t x1,
                                              uint32_t &o0, uint32_t &o1) {
  uint32_t ks2 = k0 ^ k1 ^ 0x1BD11BDAu;
  x0 += k0; x1 += k1;
#define TFR(r) { x0 += x1; x1 = (x1 << (r)) | (x1 >> (32 - (r))); x1 ^= x0; }
  TFR(13) TFR(15) TFR(26) TFR(6)
  x0 += k1;  x1 += ks2 + 1u;
  TFR(17) TFR(29) TFR(16) TFR(24)
  x0 += ks2; x1 += k0 + 2u;
  TFR(13) TFR(15) TFR(26) TFR(6)
  x0 += k0;  x1 += k1 + 3u;
  TFR(17) TFR(29) TFR(16) TFR(24)
  x0 += k1;  x1 += ks2 + 4u;
  TFR(13) TFR(15) TFR(26) TFR(6)
  x0 += ks2; x1 += k0 + 5u;
#undef TFR
  o0 = x0; o1 = x1;
}

// NOTE: parameter names must not collide with float4 member names (.x/.y/.z/.w)
#define ACC4(acc, Wv, Vv) \
  acc = fma((double)(Wv).x, (double)(Vv).x, acc); \
  acc = fma((double)(Wv).y, (double)(Vv).y, acc); \
  acc = fma((double)(Wv).z, (double)(Vv).z, acc); \
  acc = fma((double)(Wv).w, (double)(Vv).w, acc);

// Pack weights: LSTM [512,128] -> P[(k>>2)*2048 + r*4 + (k&3)]
//               attn [128,128] -> P[(k>>2)*512  + o*4 + (k&3)]
// Tail: PXE[j][r] = eWih_row_r . emb_j ; PXD likewise (dWih);
//       PXDS[r] = dWih_row_r . dec_start   (all f64)
__global__ void prep_kernel(const float* __restrict__ eWih, const float* __restrict__ eWhh,
                            const float* __restrict__ dWih, const float* __restrict__ dWhh,
                            const float* __restrict__ gWq,  const float* __restrict__ gWref,
                            const float* __restrict__ pWq,  const float* __restrict__ pWref,
                            const float* __restrict__ emb,  const float* __restrict__ dstart,
                            float* __restrict__ ws) {
  int id = blockIdx.x * blockDim.x + threadIdx.x;
  if (id < 262144) {
    int m = id >> 16, e = id & 65535;
    const float* src = (m == 0) ? eWih : (m == 1) ? eWhh : (m == 2) ? dWih : dWhh;
    int r = e >> 7, k = e & 127;
    ws[m * 65536 + (k >> 2) * 2048 + r * 4 + (k & 3)] = src[e];
  } else if (id < 327680) {
    int a = id - 262144;
    int m = a >> 14, e = a & 16383;
    const float* src = (m == 0) ? gWq : (m == 1) ? gWref : (m == 2) ? pWq : pWref;
    int o = e >> 7, k = e & 127;
    ws[262144 + m * 16384 + (k >> 2) * 512 + o * 4 + (k & 3)] = src[e];
  } else if (id < 330240) {
    int ex = id - 327680;
    double* PX = (double*)(ws + OFF_PX);
    if (ex < 2048) {
      int sel = ex >> 10;                  // 0: encoder, 1: decoder
      int j   = (ex >> 9) & 1;             // emb row
      int r   = ex & 511;                  // gate row
      const float* Wm = sel ? dWih : eWih;
      const float* V  = emb + j * 128;
      double acc = 0.0;
      for (int k = 0; k < 128; k++)
        acc = fma((double)Wm[r * 128 + k], (double)V[k], acc);
      PX[sel * 1024 + j * 512 + r] = acc;
    } else if (ex < 2560) {
      int r = ex - 2048;
      double acc = 0.0;
      for (int k = 0; k < 128; k++)
        acc = fma((double)dWih[r * 128 + k], (double)dstart[k], acc);
      PX[2048 + r] = acc;
    }
  }
}

// h-side quarter-k LSTM step for BOTH batch elements; weights loaded once.
// x-side contribution passed as precomputed f64 scalars (dxi..dxo).
// Returns h_new for be = besel; c is this lane's cell state for its besel.
static __device__ __forceinline__ float lstm_h4(
    int u, int q, int besel,
    const float4* __restrict__ PHH,
    const float* __restrict__ bih, const float* __restrict__ bhh,
    const float4* __restrict__ hA, const float4* __restrict__ hB,
    double dxi, double dxf, double dxg, double dxo,
    float &c)
{
  double eiA=0,efA=0,egA=0,eoA=0;
  double eiB=0,efB=0,egB=0,eoB=0;
  const int kb = q * 8;
#pragma unroll
  for (int kk = 0; kk < 8; kk++) {
    int k4 = kb + ((kk + 2 * q) & 7);     // per-quarter rotation: bank-spread
    float4 v0 = PHH[k4 * 512 + u];
    float4 v1 = PHH[k4 * 512 + u + 128];
    float4 v2 = PHH[k4 * 512 + u + 256];
    float4 v3 = PHH[k4 * 512 + u + 384];
    float4 hva = hA[k4]; float4 hvb = hB[k4];
    ACC4(eiA, v0, hva) ACC4(eiB, v0, hvb)
    ACC4(efA, v1, hva) ACC4(efB, v1, hvb)
    ACC4(egA, v2, hva) ACC4(egB, v2, hvb)
    ACC4(eoA, v3, hva) ACC4(eoB, v3, hvb)
  }
  RED2(eiA) RED2(efA) RED2(egA) RED2(eoA)
  RED2(eiB) RED2(efB) RED2(egB) RED2(eoB)
  double ei = besel ? eiB : eiA, ef = besel ? efB : efA;
  double eg = besel ? egB : egA, eo = besel ? eoB : eoA;
  // ((x@Wih^T + bih) + h@Whh^T) + bhh  -- XLA add tree order
  float gi = f_add(f_add(f_add((float)dxi, bih[u      ]), (float)ei), bhh[u      ]);
  float gf = f_add(f_add(f_add((float)dxf, bih[u + 128]), (float)ef), bhh[u + 128]);
  float gg = f_add(f_add(f_add((float)dxg, bih[u + 256]), (float)eg), bhh[u + 256]);
  float go = f_add(f_add(f_add((float)dxo, bih[u + 384]), (float)eo), bhh[u + 384]);
  float I = sigmoid_xla(gi);
  float F = sigmoid_xla(gf);
  float G = tanh_xla(gg);
  float O = sigmoid_xla(go);
  c = f_add(f_mul(F, c), f_mul(I, G));
  return f_mul(O, tanh_xla(c));
}

// Quarter-k 128x128 matvec for BOTH batch elements (weights loaded once).
static __device__ __forceinline__ float mv_step4(
    int u, int q, int besel,
    const float4* __restrict__ PW, const float* __restrict__ bias,
    const float4* __restrict__ xA, const float4* __restrict__ xB)
{
  double aA = 0, aB = 0;
  const int kb = q * 8;
#pragma unroll
  for (int kk = 0; kk < 8; kk++) {
    int k4 = kb + ((kk + 2 * q) & 7);
    float4 wv = PW[k4 * 128 + u];
    float4 xvA = xA[k4]; float4 xvB = xB[k4];
    ACC4(aA, wv, xvA) ACC4(aB, wv, xvB)
  }
  RED2(aA) RED2(aB)
  double tot = besel ? aB : aA;
  return f_add((float)tot, bias[u]);
}

__global__ void __launch_bounds__(512)
pnet_kernel(const float* __restrict__ bi, const float* __restrict__ emb,
            const float* __restrict__ ebih, const float* __restrict__ ebhh,
            const float* __restrict__ dbih, const float* __restrict__ dbhh,
            const float* __restrict__ gbq, const float* __restrict__ gbref, const float* __restrict__ gV,
            const float* __restrict__ pbq, const float* __restrict__ pbref, const float* __restrict__ pV,
            const float* __restrict__ dstart,
            float* __restrict__ ws, float* __restrict__ out)
{
  __shared__ __align__(16) float sRG[2][50 * RSTR];   // 52.8 KB
  __shared__ __align__(16) float sRP[2][50 * RSTR];   // 52.8 KB
  __shared__ __align__(16) float sh_h[2][128];
  __shared__ __align__(16) float sh_q[2][128];
  __shared__ __align__(16) float sh_q2[2][128];
  __shared__ float sh_att[2][64];
  __shared__ float sh_w[2][64];
  __shared__ unsigned long long sh_msk[2];
  __shared__ int sh_idx[2];

  const int tid   = threadIdx.x;            // 0..511
  const int l     = tid & 63;               // lane
  const int w     = tid >> 6;               // wave 0..7
  const int u     = w * 16 + (l & 15);      // unit 0..127
  const int q     = l >> 4;                 // k-quarter 0..3
  const int besel = q >> 1;                 // which be this lane finalizes
  const bool wq0  = (q & 1) == 0;           // writer lanes (q0 -> be0, q2 -> be1)
  const int gb2   = blockIdx.x * 2;         // first batch element of block

  const float4* PHH_E = (const float4*)(ws + OFF_PHH_E);
  const float4* PHH_D = (const float4*)(ws + OFF_PHH_D);
  const float4* PQG = (const float4*)(ws + OFF_PQG);
  const float4* PRG = (const float4*)(ws + OFF_PRG);
  const float4* PQP = (const float4*)(ws + OFF_PQP);
  const float4* PRP = (const float4*)(ws + OFF_PRP);
  const double* PXE  = (const double*)(ws + OFF_PX);         // [2][512]
  const double* PXD  = PXE + 1024;                           // [2][512]
  const double* PXDS = PXE + 2048;                           // [512]

  const float NEG_INF = -__builtin_inff();

  if (tid < 128) { sh_h[0][tid] = 0.0f; sh_h[1][tid] = 0.0f; }
  if (tid == 0) { sh_msk[0] = 0ull; sh_msk[1] = 0ull; }
  float c_st = 0.0f;
  __syncthreads();

  // ---------------- encoder + fused ref projections ----------------
  for (int t = 0; t < 50; t++) {
    // x-side via rank-2 collapse: dx = x0*PXE0[row] + x1*PXE1[row]
    float x0 = bi[(gb2 + besel) * 100 + t];
    float x1 = bi[(gb2 + besel) * 100 + 50 + t];
    double dxi = fma((double)x1, PXE[512 + u      ], (double)x0 * PXE[u      ]);
    double dxf = fma((double)x1, PXE[512 + u + 128], (double)x0 * PXE[u + 128]);
    double dxg = fma((double)x1, PXE[512 + u + 256], (double)x0 * PXE[u + 256]);
    double dxo = fma((double)x1, PXE[512 + u + 384], (double)x0 * PXE[u + 384]);
    float hn = lstm_h4(u, q, besel, PHH_E, ebih, ebhh,
                       (const float4*)sh_h[0], (const float4*)sh_h[1],
                       dxi, dxf, dxg, dxo, c_st);
    __syncthreads();                               // E1: dots done, h free
    if (wq0) sh_h[besel][u] = hn;
    __syncthreads();                               // E2: h ready
    // rg/rp[t][u] (Conv1d k=1 fused), both be, weights loaded once
    {
      double agA = 0, apA = 0, agB = 0, apB = 0;
      const int kb = q * 8;
      const float4* hA4 = (const float4*)sh_h[0];
      const float4* hB4 = (const float4*)sh_h[1];
#pragma unroll
      for (int kk = 0; kk < 8; kk++) {
        int k4 = kb + ((kk + 2 * q) & 7);
        float4 wg = PRG[k4 * 128 + u];
        float4 wp = PRP[k4 * 128 + u];
        float4 xvA = hA4[k4]; float4 xvB = hB4[k4];
        ACC4(agA, wg, xvA) ACC4(agB, wg, xvB)
        ACC4(apA, wp, xvA) ACC4(apB, wp, xvB)
      }
      RED2(agA) RED2(agB) RED2(apA) RED2(apB)
      if (wq0) {
        sRG[besel][t * RSTR + u] = f_add((float)(besel ? agB : agA), gbref[u]);
        sRP[besel][t * RSTR + u] = f_add((float)(besel ? apB : apA), pbref[u]);
      }
    }
    // t+1's h-write happens after t+1's E1 barrier -> no race with refproj.
  }

  // ---------------- decoder ----------------
  for (int t = 0; t < 50; t++) {
    // partitionable threefry:
    //   fk = fold_in(key(42), t) = tf((0,42), (0,t))
    //   k1 = split(fk, 2)[0]     = tf(fk, (0,0))   [foldlike: both words]
    uint32_t f0, f1, k1a, k1b;
    tf2x32(0u, 42u, 0u, (uint32_t)t, f0, f1);
    tf2x32(f0, f1, 0u, 0u, k1a, k1b);

    // x-side: t=0 -> dec_start (PXDS); t>0 -> embedded[b, idx] rank-2
    double dxi, dxf, dxg, dxo;
    if (t == 0) {
      dxi = PXDS[u]; dxf = PXDS[u + 128]; dxg = PXDS[u + 256]; dxo = PXDS[u + 384];
    } else {
      int idx = sh_idx[besel];
      float x0 = bi[(gb2 + besel) * 100 + idx];
      float x1 = bi[(gb2 + besel) * 100 + 50 + idx];
      dxi = fma((double)x1, PXD[512 + u      ], (double)x0 * PXD[u      ]);
      dxf = fma((double)x1, PXD[512 + u + 128], (double)x0 * PXD[u + 128]);
      dxg = fma((double)x1, PXD[512 + u + 256], (double)x0 * PXD[u + 256]);
      dxo = fma((double)x1, PXD[512 + u + 384], (double)x0 * PXD[u + 384]);
    }
    float hn = lstm_h4(u, q, besel, PHH_D, dbih, dbhh,
                       (const float4*)sh_h[0], (const float4*)sh_h[1],
                       dxi, dxf, dxg, dxo, c_st);
    __syncthreads();                                  // B1: dots done
    if (wq0) sh_h[besel][u] = hn;
    __syncthreads();                                  // B2: h ready

    // glimpse query: qg = Wq_g @ h + bq_g (both be)
    {
      float qv = mv_step4(u, q, besel, PQG, gbq,
                          (const float4*)sh_h[0], (const float4*)sh_h[1]);
      if (wq0) sh_q[besel][u] = qv;
    }
    __syncthreads();                                  // B3

    // glimpse logits: lg[s] = sum_h V[h]*tanh(qg[h]+ref_g[s][h]); 4 lanes/row
    {
      double acc = 0.0;
      const int r = tid & 255;
      const int be = tid >> 8;
      const int s = r >> 2;
      const int hf = (r & 3) * 32;
      if (r < 200) {
        const float4* rr = (const float4*)(&sRG[be][s * RSTR + hf]);
        const float4* qq = (const float4*)(&sh_q[be][hf]);
        const float4* vvp = (const float4*)(gV + hf);
#pragma unroll 2
        for (int k4 = 0; k4 < 8; k4++) {
          float4 rv = rr[k4];
          float4 qv = qq[k4];
          float4 gvv = vvp[k4];
          acc = fma((double)gvv.x, (double)tanh_xla(f_add(qv.x, rv.x)), acc);
          acc = fma((double)gvv.y, (double)tanh_xla(f_add(qv.y, rv.y)), acc);
          acc = fma((double)gvv.z, (double)tanh_xla(f_add(qv.z, rv.z)), acc);
          acc = fma((double)gvv.w, (double)tanh_xla(f_add(qv.w, rv.w)), acc);
        }
      }
      double tot = acc + shfl_xor_d(acc, 1);
      tot = tot + shfl_xor_d(tot, 2);
      if (r < 200 && (r & 3) == 0) {
        float lg = (float)tot;
        sh_att[be][s] = ((sh_msk[be] >> s) & 1ull) ? NEG_INF : lg;
      }
      if (r >= 200 && r < 214) sh_att[be][r - 150] = NEG_INF;   // pad 50..63
    }
    __syncthreads();                                  // B4

    // glimpse softmax: wave 0 -> be0, wave 4 -> be1
    if ((w & 3) == 0) {
      const int be = w >> 2;
      float v = sh_att[be][l];
      float m = v;
      for (int off = 32; off > 0; off >>= 1) m = fmaxf(m, __shfl_xor(m, off));
      float ex = (l < 50) ? expf(f_sub(v, m)) : 0.0f;
      float ss = 0.0f;
      for (int s2 = 0; s2 < 50; s2++) ss = f_add(ss, __shfl(ex, s2));
      float wv = __fdiv_rn(ex, ss);
      sh_w[be][l] = (l < 50) ? wv : 0.0f;
    }
    __syncthreads();                                  // B5

    // q2 = sum_s w[s]*ref_g[s][:]; s-halves by (q&1), combine xor16; both be
    {
      double aA = 0, aB = 0;
      const int s0 = (q & 1) * 25;
      for (int s2 = s0; s2 < s0 + 25; s2++) {
        float wvA = sh_w[0][s2];
        float wvB = sh_w[1][s2];
        aA = fma((double)sRG[0][s2 * RSTR + u], (double)wvA, aA);
        aB = fma((double)sRG[1][s2 * RSTR + u], (double)wvB, aB);
      }
      aA += shfl_xor_d(aA, 16);
      aB += shfl_xor_d(aB, 16);
      if (wq0) sh_q2[besel][u] = (float)(besel ? aB : aA);
    }
    __syncthreads();                                  // B6

    // pointer query: qp = Wq_p @ q2 + bq_p (both be)
    {
      float qv = mv_step4(u, q, besel, PQP, pbq,
                          (const float4*)sh_q2[0], (const float4*)sh_q2[1]);
      if (wq0) sh_q[besel][u] = qv;
    }
    __syncthreads();                                  // B7

    // pointer logits + 10*tanh + mask; 4 lanes/row
    {
      double acc = 0.0;
      const int r = tid & 255;
      const int be = tid >> 8;
      const int s = r >> 2;
      const int hf = (r & 3) * 32;
      if (r < 200) {
        const float4* rr = (const float4*)(&sRP[be][s * RSTR + hf]);
        const float4* qq = (const float4*)(&sh_q[be][hf]);
        const float4* vvp = (const float4*)(pV + hf);
#pragma unroll 2
        for (int k4 = 0; k4 < 8; k4++) {
          float4 rv = rr[k4];
          float4 qv = qq[k4];
          float4 pvv = vvp[k4];
          acc = fma((double)pvv.x, (double)tanh_xla(f_add(qv.x, rv.x)), acc);
          acc = fma((double)pvv.y, (double)tanh_xla(f_add(qv.y, rv.y)), acc);
          acc = fma((double)pvv.z, (double)tanh_xla(f_add(qv.z, rv.z)), acc);
          acc = fma((double)pvv.w, (double)tanh_xla(f_add(qv.w, rv.w)), acc);
        }
      }
      double tot = acc + shfl_xor_d(acc, 1);
      tot = tot + shfl_xor_d(tot, 2);
      if (r < 200 && (r & 3) == 0) {
        float lp = (float)tot;
        lp = f_mul(10.0f, tanh_xla(lp));
        sh_att[be][s] = ((sh_msk[be] >> s) & 1ull) ? NEG_INF : lp;
      }
      if (r >= 200 && r < 214) sh_att[be][r - 150] = NEG_INF;
    }
    __syncthreads();                                  // B8

    // probs output + gumbel sampling: wave 0 -> be0, wave 4 -> be1
    if ((w & 3) == 0) {
      const int be = w >> 2;
      float v = sh_att[be][l];
      float m = v;
      for (int off = 32; off > 0; off >>= 1) m = fmaxf(m, __shfl_xor(m, off));
      float ex = (l < 50) ? expf(f_sub(v, m)) : 0.0f;
      float ss = 0.0f;
      for (int s2 = 0; s2 < 50; s2++) ss = f_add(ss, __shfl(ex, s2));
      if (l < 50) out[t * 25600 + (gb2 + be) * 50 + l] = __fdiv_rn(ex, ss);

      float val = NEG_INF;
      int ii = l;
      if (l < 50) {
        int j = (gb2 + be) * 50 + l;       // flat index into (B,S) gumbel draw
        uint32_t b0, b1;
        tf2x32(k1a, k1b, 0u, (uint32_t)j, b0, b1);
        uint32_t bits = b0 ^ b1;
        float fl = __uint_as_float((bits >> 9) | 0x3f800000u) - 1.0f;  // [0,1)
        float uu = f_add(fl, TINYF);
        uu = fmaxf(TINYF, uu);
        float gum = -logf(-logf(uu));
        val = f_add(v, gum);               // -inf stays -inf for masked
      }
      // argmax, first-index tiebreak (jnp.argmax semantics)
      for (int off = 32; off > 0; off >>= 1) {
        float ov = __shfl_down(val, off);
        int   oi = __shfl_down(ii, off);
        if (ov > val || (ov == val && oi < ii)) { val = ov; ii = oi; }
      }
      if (l == 0) {
        sh_idx[be] = ii;
        sh_msk[be] |= (1ull << ii);        // masks step t+1 onward
        out[1280000 + t * 512 + gb2 + be] = (float)ii;
      }
    }
    __syncthreads();                                  // B9: sh_idx ready
    // next iteration reads sh_idx directly (no sh_x phase)
  }
}

extern "C" void kernel_launch(void* const* d_in, const int* in_sizes, int n_in,
                              void* d_out, int out_size, void* d_ws, size_t ws_size,
                              hipStream_t stream) {
  const float* bi     = (const float*)d_in[0];
  const float* emb    = (const float*)d_in[1];
  const float* eWih   = (const float*)d_in[2];
  const float* eWhh   = (const float*)d_in[3];
  const float* ebih   = (const float*)d_in[4];
  const float* ebhh   = (const float*)d_in[5];
  const float* dWih   = (const float*)d_in[6];
  const float* dWhh   = (const float*)d_in[7];
  const float* dbih   = (const float*)d_in[8];
  const float* dbhh   = (const float*)d_in[9];
  const float* gWq    = (const float*)d_in[10];
  const float* gbq    = (const float*)d_in[11];
  const float* gWref  = (const float*)d_in[12];
  const float* gbref  = (const float*)d_in[13];
  const float* gV     = (const float*)d_in[14];
  const float* pWq    = (const float*)d_in[15];
  const float* pbq    = (const float*)d_in[16];
  const float* pWref  = (const float*)d_in[17];
  const float* pbref  = (const float*)d_in[18];
  const float* pV     = (const float*)d_in[19];
  const float* dstart = (const float*)d_in[20];
  float* ws  = (float*)d_ws;
  float* out = (float*)d_out;

  hipLaunchKernelGGL(prep_kernel, dim3(1290), dim3(256), 0, stream,
                     eWih, eWhh, dWih, dWhh, gWq, gWref, pWq, pWref,
                     emb, dstart, ws);
  hipLaunchKernelGGL(pnet_kernel, dim3(256), dim3(512), 0, stream,
                     bi, emb, ebih, ebhh, dbih, dbhh,
                     gbq, gbref, gV, pbq, pbref, pV, dstart, ws, out);
}

// Round 15
// 3122.074 us; speedup vs baseline: 1.0558x; 1.0558x over previous
//
#include <hip/hip_runtime.h>
#include <stdint.h>

// PointerNet fused forward. B=512, S=50, E=H=128.
// R15 = R14 (R7 structure + rank-2 input collapse) with LATE-DX:
// the x-side scalars dx = x0*(Wih@emb0)+x1*(Wih@emb1) are computed AFTER
// the h-dot butterfly reductions, each PX f64 load consumed immediately.
// R14 passed numerically but spilled (VGPR 128, WRITE 284 MB) because dx
// was computed BEFORE the dot loop -> 4 f64 + loads live across 64 FMAs.
// With late-dx the LSTM loop carries only 8 f64 accs (vs R7's 16) + 6
// float4 transients -> strictly below R7's 100-VGPR fit.
// Structure: 256 blocks x 512 threads, 2 be/block, amortized quarter-split
// f64 h-dots (weights loaded once per block), xor16+xor32 butterfly.
// Decoder t=0 x-side: uniform path px0=px1=PXDS, x0=1, x1=0 (fma exact).
// Numerics identical to R14 (validated): f64 dots, gate sum
// f_add(f_add(f_add((float)dx,bih),(float)eh),bhh), XLA tanh poly,
// logistic-as-tanh, sequential softmax sums, f64 attention dots.
// Sampling: jax.random.categorical, THREEFRY PARTITIONABLE mode:
//   fold_in: key' = tf2x32(key, (0, t))
//   split (foldlike): k1 = tf2x32(key', (0, 0))   [both output words]
//   random_bits(32): bits[j] = o0 ^ o1 of tf2x32(k1, (0, j))
// gumbel exactly as jax._src.random; argmax with first-index ties.
// All cross-lane communication: LDS write -> __syncthreads -> read, or
// register shuffles (round-5 hardening).

#define OFF_PIH_E 0
#define OFF_PHH_E 65536
#define OFF_PIH_D 131072
#define OFF_PHH_D 196608
#define OFF_PQG   262144
#define OFF_PRG   278528
#define OFF_PQP   294912
#define OFF_PRP   311296
#define OFF_PX    327680   // doubles from here: PXE[1024], PXD[1024], PXDS[512]
// ws total: 327680 floats + 2560 doubles = 1.33 MB

#define RSTR 132   // LDS row stride for RG/RP (16B-aligned)

#define TINYF 1.1754943508222875e-38f

static __device__ __forceinline__ float f_add(float a, float b){ return __fadd_rn(a,b); }
static __device__ __forceinline__ float f_mul(float a, float b){ return __fmul_rn(a,b); }
static __device__ __forceinline__ float f_sub(float a, float b){ return __fsub_rn(a,b); }

static __device__ __forceinline__ double shfl_xor_d(double v, int mask) {
  long long x = __double_as_longlong(v);
  int lo = (int)(x & 0xffffffffll);
  int hi = (int)(x >> 32);
  lo = __shfl_xor(lo, mask);
  hi = __shfl_xor(hi, mask);
  return __longlong_as_double(((long long)hi << 32) | (unsigned long long)(unsigned int)lo);
}
#define RED2(x) { x += shfl_xor_d(x, 16); x += shfl_xor_d(x, 32); }

// XLA CPU tanh: elemental_ir_emitter rational approximation, unfused mul/add.
static __device__ __forceinline__ float tanh_xla(float x) {
  float xc = fminf(fmaxf(x, -7.90531110763549805f), 7.90531110763549805f);
  float x2 = f_mul(xc, xc);
  float p;
  p = -2.76076847742355e-16f;
  p = f_add(f_mul(p, x2),  2.00018790482477e-13f);
  p = f_add(f_mul(p, x2), -8.60467152213735e-11f);
  p = f_add(f_mul(p, x2),  5.12229709037114e-08f);
  p = f_add(f_mul(p, x2),  1.48572235717979e-05f);
  p = f_add(f_mul(p, x2),  6.37261928875436e-04f);
  p = f_add(f_mul(p, x2),  4.89352455891786e-03f);
  p = f_mul(xc, p);
  float q;
  q = 1.19825839466702e-06f;
  q = f_add(f_mul(q, x2), 1.18534705686654e-04f);
  q = f_add(f_mul(q, x2), 2.26843463243900e-03f);
  q = f_add(f_mul(q, x2), 4.89352518554385e-03f);
  float r = __fdiv_rn(p, q);
  return (fabsf(x) < 0.0004f) ? x : r;
}

// XLA logistic expansion: 0.5 + 0.5*tanh(0.5*x)
static __device__ __forceinline__ float sigmoid_xla(float x) {
  return f_add(0.5f, f_mul(0.5f, tanh_xla(f_mul(0.5f, x))));
}

// Threefry-2x32, 20 rounds (JAX key schedule)
static __device__ __forceinline__ void tf2x32(uint32_t k0, uint32_t k1,
                                              uint32_t x0, uint32_t x1,
                                              uint32_t &o0, uint32_t &o1) {
  uint32_t ks2 = k0 ^ k1 ^ 0x1BD11BDAu;
  x0 += k0; x1 += k1;
#define TFR(r) { x0 += x1; x1 = (x1 << (r)) | (x1 >> (32 - (r))); x1 ^= x0; }
  TFR(13) TFR(15) TFR(26) TFR(6)
  x0 += k1;  x1 += ks2 + 1u;
  TFR(17) TFR(29) TFR(16) TFR(24)
  x0 += ks2; x1 += k0 + 2u;
  TFR(13) TFR(15) TFR(26) TFR(6)
  x0 += k0;  x1 += k1 + 3u;
  TFR(17) TFR(29) TFR(16) TFR(24)
  x0 += k1;  x1 += ks2 + 4u;
  TFR(13) TFR(15) TFR(26) TFR(6)
  x0 += ks2; x1 += k0 + 5u;
#undef TFR
  o0 = x0; o1 = x1;
}

// NOTE: parameter names must not collide with float4 member names (.x/.y/.z/.w)
#define ACC4(acc, Wv, Vv) \
  acc = fma((double)(Wv).x, (double)(Vv).x, acc); \
  acc = fma((double)(Wv).y, (double)(Vv).y, acc); \
  acc = fma((double)(Wv).z, (double)(Vv).z, acc); \
  acc = fma((double)(Wv).w, (double)(Vv).w, acc);

// Pack weights: LSTM [512,128] -> P[(k>>2)*2048 + r*4 + (k&3)]
//               attn [128,128] -> P[(k>>2)*512  + o*4 + (k&3)]
// Tail: PXE[j][r] = eWih_row_r . emb_j ; PXD likewise (dWih);
//       PXDS[r] = dWih_row_r . dec_start   (all f64)
__global__ void prep_kernel(const float* __restrict__ eWih, const float* __restrict__ eWhh,
                            const float* __restrict__ dWih, const float* __restrict__ dWhh,
                            const float* __restrict__ gWq,  const float* __restrict__ gWref,
                            const float* __restrict__ pWq,  const float* __restrict__ pWref,
                            const float* __restrict__ emb,  const float* __restrict__ dstart,
                            float* __restrict__ ws) {
  int id = blockIdx.x * blockDim.x + threadIdx.x;
  if (id < 262144) {
    int m = id >> 16, e = id & 65535;
    const float* src = (m == 0) ? eWih : (m == 1) ? eWhh : (m == 2) ? dWih : dWhh;
    int r = e >> 7, k = e & 127;
    ws[m * 65536 + (k >> 2) * 2048 + r * 4 + (k & 3)] = src[e];
  } else if (id < 327680) {
    int a = id - 262144;
    int m = a >> 14, e = a & 16383;
    const float* src = (m == 0) ? gWq : (m == 1) ? gWref : (m == 2) ? pWq : pWref;
    int o = e >> 7, k = e & 127;
    ws[262144 + m * 16384 + (k >> 2) * 512 + o * 4 + (k & 3)] = src[e];
  } else if (id < 330240) {
    int ex = id - 327680;
    double* PX = (double*)(ws + OFF_PX);
    if (ex < 2048) {
      int sel = ex >> 10;                  // 0: encoder, 1: decoder
      int j   = (ex >> 9) & 1;             // emb row
      int r   = ex & 511;                  // gate row
      const float* Wm = sel ? dWih : eWih;
      const float* V  = emb + j * 128;
      double acc = 0.0;
      for (int k = 0; k < 128; k++)
        acc = fma((double)Wm[r * 128 + k], (double)V[k], acc);
      PX[sel * 1024 + j * 512 + r] = acc;
    } else if (ex < 2560) {
      int r = ex - 2048;
      double acc = 0.0;
      for (int k = 0; k < 128; k++)
        acc = fma((double)dWih[r * 128 + k], (double)dstart[k], acc);
      PX[2048 + r] = acc;
    }
  }
}

// h-side quarter-k LSTM step for BOTH batch elements; weights loaded once.
// x-side: computed LATE from px0/px1 (rank-2 collapse), each load consumed
// immediately by its gate sum -> minimal live ranges.
static __device__ __forceinline__ float lstm_h4(
    int u, int q, int besel,
    const float4* __restrict__ PHH,
    const float* __restrict__ bih, const float* __restrict__ bhh,
    const float4* __restrict__ hA, const float4* __restrict__ hB,
    const double* __restrict__ px0, const double* __restrict__ px1,
    float x0, float x1,
    float &c)
{
  double eiA=0,efA=0,egA=0,eoA=0;
  double eiB=0,efB=0,egB=0,eoB=0;
  const int kb = q * 8;
#pragma unroll
  for (int kk = 0; kk < 8; kk++) {
    int k4 = kb + ((kk + 2 * q) & 7);     // per-quarter rotation: bank-spread
    float4 v0 = PHH[k4 * 512 + u];
    float4 v1 = PHH[k4 * 512 + u + 128];
    float4 v2 = PHH[k4 * 512 + u + 256];
    float4 v3 = PHH[k4 * 512 + u + 384];
    float4 hvA = hA[k4]; float4 hvB = hB[k4];
    ACC4(eiA, v0, hvA) ACC4(efA, v1, hvA) ACC4(egA, v2, hvA) ACC4(eoA, v3, hvA)
    ACC4(eiB, v0, hvB) ACC4(efB, v1, hvB) ACC4(egB, v2, hvB) ACC4(eoB, v3, hvB)
  }
  RED2(eiA) RED2(efA) RED2(egA) RED2(eoA)
  RED2(eiB) RED2(efB) RED2(egB) RED2(eoB)
  double ei = besel ? eiB : eiA, ef = besel ? efB : efA;
  double eg = besel ? egB : egA, eo = besel ? eoB : eoA;
  // x-side rank-2, late: dx = x0*px0[row] + x1*px1[row], consumed at once.
  // ((x@Wih^T + bih) + h@Whh^T) + bhh  -- XLA add tree order
  double dxi = fma((double)x1, px1[u      ], (double)x0 * px0[u      ]);
  float gi = f_add(f_add(f_add((float)dxi, bih[u      ]), (float)ei), bhh[u      ]);
  double dxf = fma((double)x1, px1[u + 128], (double)x0 * px0[u + 128]);
  float gf = f_add(f_add(f_add((float)dxf, bih[u + 128]), (float)ef), bhh[u + 128]);
  double dxg = fma((double)x1, px1[u + 256], (double)x0 * px0[u + 256]);
  float gg = f_add(f_add(f_add((float)dxg, bih[u + 256]), (float)eg), bhh[u + 256]);
  double dxo = fma((double)x1, px1[u + 384], (double)x0 * px0[u + 384]);
  float go = f_add(f_add(f_add((float)dxo, bih[u + 384]), (float)eo), bhh[u + 384]);
  float I = sigmoid_xla(gi);
  float F = sigmoid_xla(gf);
  float G = tanh_xla(gg);
  float O = sigmoid_xla(go);
  c = f_add(f_mul(F, c), f_mul(I, G));
  return f_mul(O, tanh_xla(c));
}

// Quarter-k 128x128 matvec for BOTH batch elements (weights loaded once).
static __device__ __forceinline__ float mv_step4(
    int u, int q, int besel,
    const float4* __restrict__ PW, const float* __restrict__ bias,
    const float4* __restrict__ xA, const float4* __restrict__ xB)
{
  double aA = 0, aB = 0;
  const int kb = q * 8;
#pragma unroll
  for (int kk = 0; kk < 8; kk++) {
    int k4 = kb + ((kk + 2 * q) & 7);
    float4 wv = PW[k4 * 128 + u];
    float4 xvA = xA[k4]; float4 xvB = xB[k4];
    ACC4(aA, wv, xvA) ACC4(aB, wv, xvB)
  }
  RED2(aA) RED2(aB)
  double tot = besel ? aB : aA;
  return f_add((float)tot, bias[u]);
}

__global__ void __launch_bounds__(512)
pnet_kernel(const float* __restrict__ bi, const float* __restrict__ emb,
            const float* __restrict__ ebih, const float* __restrict__ ebhh,
            const float* __restrict__ dbih, const float* __restrict__ dbhh,
            const float* __restrict__ gbq, const float* __restrict__ gbref, const float* __restrict__ gV,
            const float* __restrict__ pbq, const float* __restrict__ pbref, const float* __restrict__ pV,
            const float* __restrict__ dstart,
            float* __restrict__ ws, float* __restrict__ out)
{
  __shared__ __align__(16) float sRG[2][50 * RSTR];   // 52.8 KB
  __shared__ __align__(16) float sRP[2][50 * RSTR];   // 52.8 KB
  __shared__ __align__(16) float sh_h[2][128];
  __shared__ __align__(16) float sh_q[2][128];
  __shared__ __align__(16) float sh_q2[2][128];
  __shared__ float sh_att[2][64];
  __shared__ float sh_w[2][64];
  __shared__ unsigned long long sh_msk[2];
  __shared__ int sh_idx[2];

  const int tid   = threadIdx.x;            // 0..511
  const int l     = tid & 63;               // lane
  const int w     = tid >> 6;               // wave 0..7
  const int u     = w * 16 + (l & 15);      // unit 0..127
  const int q     = l >> 4;                 // k-quarter 0..3
  const int besel = q >> 1;                 // which be this lane finalizes
  const bool wq0  = (q & 1) == 0;           // writer lanes (q0 -> be0, q2 -> be1)
  const int gb2   = blockIdx.x * 2;         // first batch element of block

  const float4* PHH_E = (const float4*)(ws + OFF_PHH_E);
  const float4* PHH_D = (const float4*)(ws + OFF_PHH_D);
  const float4* PQG = (const float4*)(ws + OFF_PQG);
  const float4* PRG = (const float4*)(ws + OFF_PRG);
  const float4* PQP = (const float4*)(ws + OFF_PQP);
  const float4* PRP = (const float4*)(ws + OFF_PRP);
  const double* PXE  = (const double*)(ws + OFF_PX);         // [2][512]
  const double* PXD  = PXE + 1024;                           // [2][512]
  const double* PXDS = PXE + 2048;                           // [512]

  const float NEG_INF = -__builtin_inff();

  if (tid < 128) { sh_h[0][tid] = 0.0f; sh_h[1][tid] = 0.0f; }
  if (tid == 0) { sh_msk[0] = 0ull; sh_msk[1] = 0ull; }
  float c_st = 0.0f;
  __syncthreads();

  // ---------------- encoder + fused ref projections ----------------
  for (int t = 0; t < 50; t++) {
    float x0 = bi[(gb2 + besel) * 100 + t];
    float x1 = bi[(gb2 + besel) * 100 + 50 + t];
    float hn = lstm_h4(u, q, besel, PHH_E, ebih, ebhh,
                       (const float4*)sh_h[0], (const float4*)sh_h[1],
                       PXE, PXE + 512, x0, x1, c_st);
    __syncthreads();                               // E1: dots done, h free
    if (wq0) sh_h[besel][u] = hn;
    __syncthreads();                               // E2: h ready
    // rg/rp[t][u] (Conv1d k=1 fused), both be, weights loaded once
    {
      double agA = 0, apA = 0, agB = 0, apB = 0;
      const int kb = q * 8;
      const float4* hA4 = (const float4*)sh_h[0];
      const float4* hB4 = (const float4*)sh_h[1];
#pragma unroll
      for (int kk = 0; kk < 8; kk++) {
        int k4 = kb + ((kk + 2 * q) & 7);
        float4 wg = PRG[k4 * 128 + u];
        float4 wp = PRP[k4 * 128 + u];
        float4 xvA = hA4[k4]; float4 xvB = hB4[k4];
        ACC4(agA, wg, xvA) ACC4(agB, wg, xvB)
        ACC4(apA, wp, xvA) ACC4(apB, wp, xvB)
      }
      RED2(agA) RED2(agB) RED2(apA) RED2(apB)
      if (wq0) {
        sRG[besel][t * RSTR + u] = f_add((float)(besel ? agB : agA), gbref[u]);
        sRP[besel][t * RSTR + u] = f_add((float)(besel ? apB : apA), pbref[u]);
      }
    }
    // t+1's h-write happens after t+1's E1 barrier -> no race with refproj.
  }

  // ---------------- decoder ----------------
  for (int t = 0; t < 50; t++) {
    // partitionable threefry:
    //   fk = fold_in(key(42), t) = tf((0,42), (0,t))
    //   k1 = split(fk, 2)[0]     = tf(fk, (0,0))   [foldlike: both words]
    uint32_t f0, f1, k1a, k1b;
    tf2x32(0u, 42u, 0u, (uint32_t)t, f0, f1);
    tf2x32(f0, f1, 0u, 0u, k1a, k1b);

    // x-side source: t=0 -> PXDS with (x0,x1)=(1,0) [fma exact];
    //                t>0 -> rank-2 embedded[b, idx]
    const double* px0;
    const double* px1;
    float x0, x1;
    if (t == 0) {
      px0 = PXDS; px1 = PXDS; x0 = 1.0f; x1 = 0.0f;
    } else {
      int idx = sh_idx[besel];
      px0 = PXD; px1 = PXD + 512;
      x0 = bi[(gb2 + besel) * 100 + idx];
      x1 = bi[(gb2 + besel) * 100 + 50 + idx];
    }
    float hn = lstm_h4(u, q, besel, PHH_D, dbih, dbhh,
                       (const float4*)sh_h[0], (const float4*)sh_h[1],
                       px0, px1, x0, x1, c_st);
    __syncthreads();                                  // B1: dots done
    if (wq0) sh_h[besel][u] = hn;
    __syncthreads();                                  // B2: h ready

    // glimpse query: qg = Wq_g @ h + bq_g (both be)
    {
      float qv = mv_step4(u, q, besel, PQG, gbq,
                          (const float4*)sh_h[0], (const float4*)sh_h[1]);
      if (wq0) sh_q[besel][u] = qv;
    }
    __syncthreads();                                  // B3

    // glimpse logits: lg[s] = sum_h V[h]*tanh(qg[h]+ref_g[s][h]); 4 lanes/row
    {
      double acc = 0.0;
      const int r = tid & 255;
      const int be = tid >> 8;
      const int s = r >> 2;
      const int hf = (r & 3) * 32;
      if (r < 200) {
        const float4* rr = (const float4*)(&sRG[be][s * RSTR + hf]);
        const float4* qq = (const float4*)(&sh_q[be][hf]);
        const float4* vvp = (const float4*)(gV + hf);
#pragma unroll 2
        for (int k4 = 0; k4 < 8; k4++) {
          float4 rv = rr[k4];
          float4 qv = qq[k4];
          float4 gvv = vvp[k4];
          acc = fma((double)gvv.x, (double)tanh_xla(f_add(qv.x, rv.x)), acc);
          acc = fma((double)gvv.y, (double)tanh_xla(f_add(qv.y, rv.y)), acc);
          acc = fma((double)gvv.z, (double)tanh_xla(f_add(qv.z, rv.z)), acc);
          acc = fma((double)gvv.w, (double)tanh_xla(f_add(qv.w, rv.w)), acc);
        }
      }
      double tot = acc + shfl_xor_d(acc, 1);
      tot = tot + shfl_xor_d(tot, 2);
      if (r < 200 && (r & 3) == 0) {
        float lg = (float)tot;
        sh_att[be][s] = ((sh_msk[be] >> s) & 1ull) ? NEG_INF : lg;
      }
      if (r >= 200 && r < 214) sh_att[be][r - 150] = NEG_INF;   // pad 50..63
    }
    __syncthreads();                                  // B4

    // glimpse softmax: wave 0 -> be0, wave 4 -> be1
    if ((w & 3) == 0) {
      const int be = w >> 2;
      float v = sh_att[be][l];
      float m = v;
      for (int off = 32; off > 0; off >>= 1) m = fmaxf(m, __shfl_xor(m, off));
      float ex = (l < 50) ? expf(f_sub(v, m)) : 0.0f;
      float ss = 0.0f;
      for (int s2 = 0; s2 < 50; s2++) ss = f_add(ss, __shfl(ex, s2));
      float wv = __fdiv_rn(ex, ss);
      sh_w[be][l] = (l < 50) ? wv : 0.0f;
    }
    __syncthreads();                                  // B5

    // q2 = sum_s w[s]*ref_g[s][:]; s-halves by (q&1), combine xor16; both be
    {
      double aA = 0, aB = 0;
      const int s0 = (q & 1) * 25;
      for (int s2 = s0; s2 < s0 + 25; s2++) {
        float wvA = sh_w[0][s2];
        float wvB = sh_w[1][s2];
        aA = fma((double)sRG[0][s2 * RSTR + u], (double)wvA, aA);
        aB = fma((double)sRG[1][s2 * RSTR + u], (double)wvB, aB);
      }
      aA += shfl_xor_d(aA, 16);
      aB += shfl_xor_d(aB, 16);
      if (wq0) sh_q2[besel][u] = (float)(besel ? aB : aA);
    }
    __syncthreads();                                  // B6

    // pointer query: qp = Wq_p @ q2 + bq_p (both be)
    {
      float qv = mv_step4(u, q, besel, PQP, pbq,
                          (const float4*)sh_q2[0], (const float4*)sh_q2[1]);
      if (wq0) sh_q[besel][u] = qv;
    }
    __syncthreads();                                  // B7

    // pointer logits + 10*tanh + mask; 4 lanes/row
    {
      double acc = 0.0;
      const int r = tid & 255;
      const int be = tid >> 8;
      const int s = r >> 2;
      const int hf = (r & 3) * 32;
      if (r < 200) {
        const float4* rr = (const float4*)(&sRP[be][s * RSTR + hf]);
        const float4* qq = (const float4*)(&sh_q[be][hf]);
        const float4* vvp = (const float4*)(pV + hf);
#pragma unroll 2
        for (int k4 = 0; k4 < 8; k4++) {
          float4 rv = rr[k4];
          float4 qv = qq[k4];
          float4 pvv = vvp[k4];
          acc = fma((double)pvv.x, (double)tanh_xla(f_add(qv.x, rv.x)), acc);
          acc = fma((double)pvv.y, (double)tanh_xla(f_add(qv.y, rv.y)), acc);
          acc = fma((double)pvv.z, (double)tanh_xla(f_add(qv.z, rv.z)), acc);
          acc = fma((double)pvv.w, (double)tanh_xla(f_add(qv.w, rv.w)), acc);
        }
      }
      double tot = acc + shfl_xor_d(acc, 1);
      tot = tot + shfl_xor_d(tot, 2);
      if (r < 200 && (r & 3) == 0) {
        float lp = (float)tot;
        lp = f_mul(10.0f, tanh_xla(lp));
        sh_att[be][s] = ((sh_msk[be] >> s) & 1ull) ? NEG_INF : lp;
      }
      if (r >= 200 && r < 214) sh_att[be][r - 150] = NEG_INF;
    }
    __syncthreads();                                  // B8

    // probs output + gumbel sampling: wave 0 -> be0, wave 4 -> be1
    if ((w & 3) == 0) {
      const int be = w >> 2;
      float v = sh_att[be][l];
      float m = v;
      for (int off = 32; off > 0; off >>= 1) m = fmaxf(m, __shfl_xor(m, off));
      float ex = (l < 50) ? expf(f_sub(v, m)) : 0.0f;
      float ss = 0.0f;
      for (int s2 = 0; s2 < 50; s2++) ss = f_add(ss, __shfl(ex, s2));
      if (l < 50) out[t * 25600 + (gb2 + be) * 50 + l] = __fdiv_rn(ex, ss);

      float val = NEG_INF;
      int ii = l;
      if (l < 50) {
        int j = (gb2 + be) * 50 + l;       // flat index into (B,S) gumbel draw
        uint32_t b0, b1;
        tf2x32(k1a, k1b, 0u, (uint32_t)j, b0, b1);
        uint32_t bits = b0 ^ b1;
        float fl = __uint_as_float((bits >> 9) | 0x3f800000u) - 1.0f;  // [0,1)
        float uu = f_add(fl, TINYF);
        uu = fmaxf(TINYF, uu);
        float gum = -logf(-logf(uu));
        val = f_add(v, gum);               // -inf stays -inf for masked
      }
      // argmax, first-index tiebreak (jnp.argmax semantics)
      for (int off = 32; off > 0; off >>= 1) {
        float ov = __shfl_down(val, off);
        int   oi = __shfl_down(ii, off);
        if (ov > val || (ov == val && oi < ii)) { val = ov; ii = oi; }
      }
      if (l == 0) {
        sh_idx[be] = ii;
        sh_msk[be] |= (1ull << ii);        // masks step t+1 onward
        out[1280000 + t * 512 + gb2 + be] = (float)ii;
      }
    }
    __syncthreads();                                  // B9: sh_idx ready
    // next iteration reads sh_idx directly (no sh_x phase)
  }
}

extern "C" void kernel_launch(void* const* d_in, const int* in_sizes, int n_in,
                              void* d_out, int out_size, void* d_ws, size_t ws_size,
                              hipStream_t stream) {
  const float* bi     = (const float*)d_in[0];
  const float* emb    = (const float*)d_in[1];
  const float* eWih   = (const float*)d_in[2];
  const float* eWhh   = (const float*)d_in[3];
  const float* ebih   = (const float*)d_in[4];
  const float* ebhh   = (const float*)d_in[5];
  const float* dWih   = (const float*)d_in[6];
  const float* dWhh   = (const float*)d_in[7];
  const float* dbih   = (const float*)d_in[8];
  const float* dbhh   = (const float*)d_in[9];
  const float* gWq    = (const float*)d_in[10];
  const float* gbq    = (const float*)d_in[11];
  const float* gWref  = (const float*)d_in[12];
  const float* gbref  = (const float*)d_in[13];
  const float* gV     = (const float*)d_in[14];
  const float* pWq    = (const float*)d_in[15];
  const float* pbq    = (const float*)d_in[16];
  const float* pWref  = (const float*)d_in[17];
  const float* pbref  = (const float*)d_in[18];
  const float* pV     = (const float*)d_in[19];
  const float* dstart = (const float*)d_in[20];
  float* ws  = (float*)d_ws;
  float* out = (float*)d_out;

  hipLaunchKernelGGL(prep_kernel, dim3(1290), dim3(256), 0, stream,
                     eWih, eWhh, dWih, dWhh, gWq, gWref, pWq, pWref,
                     emb, dstart, ws);
  hipLaunchKernelGGL(pnet_kernel, dim3(256), dim3(512), 0, stream,
                     bi, emb, ebih, ebhh, dbih, dbhh,
                     gbq, gbref, gV, pbq, pbref, pV, dstart, ws, out);
}